// Round 9
// baseline (524.721 us; speedup 1.0000x reference)
//
#include <hip/hip_runtime.h>
#include <hip/hip_cooperative_groups.h>
#include <stdint.h>

namespace cg = cooperative_groups;

// SAGEConv (mean aggr, no bias): out = segment_mean(x[src], dst) @ W_l + x @ W_r
// Single cooperative kernel, 4 phases with grid.sync() between:
//   P1 cvt : x -> bf16 xb, Wl/Wr -> transposed bf16, cursorB[b]=b*CAP, offsets[N]=E
//   P2 part: partition edges into padded dst-buckets (dst>>9), counts in cursorB
//   P3 sub : per bucket: counts -> CSR base -> node scan -> offsets + scatter
//   P4 fuse: gather-mean (wave/node-quad) -> LDS bf16 tile -> MFMA GEMM

#define FDIM 64
#define NPB 512
#define PART_T 2048
#define MAXBKT 256
#define CAP 8192

typedef __attribute__((ext_vector_type(8))) short bf16x8;
typedef __attribute__((ext_vector_type(4))) float f32x4;

__device__ inline ushort f2b(float v) {
  union { float f; uint32_t u; } c; c.f = v;
  return (ushort)((c.u + 0x7FFF + ((c.u >> 16) & 1)) >> 16);  // RNE
}
__device__ inline float b2f(ushort h) {
  union { uint32_t u; float f; } c; c.u = ((uint32_t)h) << 16;
  return c.f;
}

union SharedU {
  struct {
    int cnt[MAXBKT], sc[MAXBKT], excl0[MAXBKT], cursorL[MAXBKT], gbase[MAXBKT];
    int2 buf[PART_T];
  } part;  // 5 KB + 16 KB = 21 KB
  struct {
    int cnt[NPB];   // counts, then cursors
    int sc2[256];   // pair-sum scan
    int red[256];   // csr0 reduction
  } sub;   // 4 KB
  struct {
    ushort mean[16][72];
  } fuse;  // 2.3 KB
};

__global__ __launch_bounds__(256, 4) void k_all(
    const float* __restrict__ x, const int* __restrict__ esrc,
    const int* __restrict__ edst, const float* __restrict__ Wl,
    const float* __restrict__ Wr, float* __restrict__ out,
    ushort* __restrict__ xb, ushort* __restrict__ WlT, ushort* __restrict__ WrT,
    int* __restrict__ cursorB, int* __restrict__ offsets,
    int2* __restrict__ pairs, int* __restrict__ sorted_src, int n_nodes,
    int n_edges) {
  __shared__ SharedU sh;
  cg::grid_group grid = cg::this_grid();
  const int t = threadIdx.x;
  const int gtid = blockIdx.x * 256 + t;
  const int nthr = gridDim.x * 256;

  // ---------------- P1: convert + init ----------------
  const int xquads = n_nodes * (FDIM / 4);
  for (int i = gtid; i < xquads; i += nthr) {
    const float4 v = ((const float4*)x)[i];
    ushort4 o;
    o.x = f2b(v.x); o.y = f2b(v.y); o.z = f2b(v.z); o.w = f2b(v.w);
    ((ushort4*)xb)[i] = o;
  }
  if (gtid < FDIM * FDIM) {
    const int f = gtid >> 6, k = gtid & 63;
    WlT[f * 64 + k] = f2b(Wl[k * 64 + f]);
    WrT[f * 64 + k] = f2b(Wr[k * 64 + f]);
  }
  if (gtid < MAXBKT) cursorB[gtid] = gtid * CAP;
  if (gtid == 0) offsets[n_nodes] = n_edges;
  grid.sync();

  // ---------------- P2: partition into padded buckets ----------------
  const int EB = (n_edges + PART_T - 1) / PART_T;
  for (int chunk = blockIdx.x; chunk < EB; chunk += gridDim.x) {
    const int base = chunk * PART_T;
    const int nvalid = min(n_edges - base, PART_T);
    __syncthreads();  // protect LDS reuse across iterations
    sh.part.cnt[t] = 0;
    __syncthreads();

    int s[8], d[8], bk[8];
#pragma unroll
    for (int i = 0; i < 8; ++i) {
      const int e = base + i * 256 + t;
      if (e < n_edges) {
        s[i] = esrc[e];
        d[i] = edst[e];
        bk[i] = d[i] >> 9;
        atomicAdd(&sh.part.cnt[bk[i]], 1);
      } else {
        bk[i] = -1;
      }
    }
    __syncthreads();

    sh.part.sc[t] = sh.part.cnt[t];
    __syncthreads();
    for (int off = 1; off < MAXBKT; off <<= 1) {
      int v = (t >= off) ? sh.part.sc[t - off] : 0;
      __syncthreads();
      sh.part.sc[t] += v;
      __syncthreads();
    }
    sh.part.excl0[t] = sh.part.sc[t] - sh.part.cnt[t];
    sh.part.cursorL[t] = sh.part.excl0[t];
    __syncthreads();

#pragma unroll
    for (int i = 0; i < 8; ++i) {
      if (bk[i] >= 0) {
        int slot = atomicAdd(&sh.part.cursorL[bk[i]], 1);
        sh.part.buf[slot] = make_int2(s[i], d[i]);
      }
    }
    __syncthreads();

    if (sh.part.cnt[t] > 0) sh.part.gbase[t] = atomicAdd(&cursorB[t], sh.part.cnt[t]);
    __syncthreads();

    for (int idx = t; idx < nvalid; idx += 256) {
      int2 p = sh.part.buf[idx];
      int b = p.y >> 9;
      pairs[sh.part.gbase[b] + (idx - sh.part.excl0[b])] = p;
    }
  }
  grid.sync();

  // ---------------- P3: per-bucket CSR build + scatter ----------------
  const int NBKT = (n_nodes + NPB - 1) / NPB;
  for (int b = blockIdx.x; b < NBKT; b += gridDim.x) {
    const int nodebase = b * NPB;
    const int mycnt = cursorB[b] - b * CAP;
    const int rbase = b * CAP;
    __syncthreads();  // protect LDS reuse
    sh.sub.cnt[t] = 0;
    sh.sub.cnt[t + 256] = 0;
    __syncthreads();
    for (int i = t; i < mycnt; i += 256)
      atomicAdd(&sh.sub.cnt[pairs[rbase + i].y - nodebase], 1);
    int partial = 0;
    for (int i = t; i < b; i += 256) partial += cursorB[i] - i * CAP;
    sh.sub.red[t] = partial;
    __syncthreads();
    for (int off = 128; off > 0; off >>= 1) {
      if (t < off) sh.sub.red[t] += sh.sub.red[t + off];
      __syncthreads();
    }
    const int csr0 = sh.sub.red[0];
    // pairwise scan: thread t owns nodes 2t, 2t+1
    const int c0 = sh.sub.cnt[2 * t], c1 = sh.sub.cnt[2 * t + 1];
    const int p = c0 + c1;
    sh.sub.sc2[t] = p;
    __syncthreads();
    for (int off = 1; off < 256; off <<= 1) {
      int v = (t >= off) ? sh.sub.sc2[t - off] : 0;
      __syncthreads();
      sh.sub.sc2[t] += v;
      __syncthreads();
    }
    const int e0 = csr0 + sh.sub.sc2[t] - p;
    const int e1 = e0 + c0;
    const int node0 = nodebase + 2 * t;
    if (node0 < n_nodes) offsets[node0] = e0;
    if (node0 + 1 < n_nodes) offsets[node0 + 1] = e1;
    __syncthreads();
    sh.sub.cnt[2 * t] = e0;  // reuse as global cursors
    sh.sub.cnt[2 * t + 1] = e1;
    __syncthreads();
    for (int i = t; i < mycnt; i += 256) {
      int2 pr = pairs[rbase + i];
      int pos = atomicAdd(&sh.sub.cnt[pr.y - nodebase], 1);
      sorted_src[pos] = pr.x;
    }
  }
  grid.sync();

  // ---------------- P4: fused gather-mean + MFMA GEMM ----------------
  const int wave = t >> 6;
  const int lane = t & 63;
  const int c = lane & 15;
  const int g = lane >> 4;
  const int ntiles = (n_nodes + 15) / 16;
  for (int tile = blockIdx.x; tile < ntiles; tile += gridDim.x) {
    const int nodebase = tile * 16;
    __syncthreads();  // protect meanLds reuse
#pragma unroll
    for (int q = 0; q < 4; ++q) {
      const int r = wave * 4 + q;
      const int node = nodebase + r;
      if (node >= n_nodes) break;
      const int start = offsets[node];
      const int end = offsets[node + 1];
      const int degree = end - start;

      float s0 = 0.f, s1 = 0.f, s2 = 0.f, s3 = 0.f;
      for (int base = start; base < end; base += 64) {
        const int e = base + lane;
        const int idx = (e < end) ? sorted_src[e] : node;  // pad = safe address
        const int nIn = min(end - base, 64);
        const int G = (nIn + 3) >> 2;
#pragma unroll 4
        for (int j = 0; j < G; ++j) {
          const int sub = 4 * j + g;
          const int se = __shfl(idx, sub, 64);
          const float wm = (sub < nIn) ? 1.0f : 0.0f;
          const ushort4 h = *(const ushort4*)(xb + (size_t)se * FDIM + (c << 2));
          s0 = fmaf(b2f(h.x), wm, s0);
          s1 = fmaf(b2f(h.y), wm, s1);
          s2 = fmaf(b2f(h.z), wm, s2);
          s3 = fmaf(b2f(h.w), wm, s3);
        }
      }
      s0 += __shfl_xor(s0, 16, 64);
      s1 += __shfl_xor(s1, 16, 64);
      s2 += __shfl_xor(s2, 16, 64);
      s3 += __shfl_xor(s3, 16, 64);
      s0 += __shfl_xor(s0, 32, 64);
      s1 += __shfl_xor(s1, 32, 64);
      s2 += __shfl_xor(s2, 32, 64);
      s3 += __shfl_xor(s3, 32, 64);
      if (g == 0) {
        const float inv = 1.0f / (float)max(degree, 1);
        ushort4 mb;
        mb.x = f2b(s0 * inv);
        mb.y = f2b(s1 * inv);
        mb.z = f2b(s2 * inv);
        mb.w = f2b(s3 * inv);
        *(ushort4*)(&sh.fuse.mean[r][c << 2]) = mb;
      }
    }
    __syncthreads();

    const int m = lane & 15;
    const int quad = lane >> 4;
    bf16x8 am0 = *(const bf16x8*)(&sh.fuse.mean[m][quad * 8]);
    bf16x8 am1 = *(const bf16x8*)(&sh.fuse.mean[m][32 + quad * 8]);
    const int arow = min(nodebase + m, n_nodes - 1);
    bf16x8 ax0 = *(const bf16x8*)(xb + (size_t)arow * FDIM + quad * 8);
    bf16x8 ax1 = *(const bf16x8*)(xb + (size_t)arow * FDIM + 32 + quad * 8);
    const int f = wave * 16 + m;
    bf16x8 bl0 = *(const bf16x8*)(WlT + (size_t)f * FDIM + quad * 8);
    bf16x8 bl1 = *(const bf16x8*)(WlT + (size_t)f * FDIM + 32 + quad * 8);
    bf16x8 br0 = *(const bf16x8*)(WrT + (size_t)f * FDIM + quad * 8);
    bf16x8 br1 = *(const bf16x8*)(WrT + (size_t)f * FDIM + 32 + quad * 8);
    f32x4 acc = {0.f, 0.f, 0.f, 0.f};
    acc = __builtin_amdgcn_mfma_f32_16x16x32_bf16(am0, bl0, acc, 0, 0, 0);
    acc = __builtin_amdgcn_mfma_f32_16x16x32_bf16(am1, bl1, acc, 0, 0, 0);
    acc = __builtin_amdgcn_mfma_f32_16x16x32_bf16(ax0, br0, acc, 0, 0, 0);
    acc = __builtin_amdgcn_mfma_f32_16x16x32_bf16(ax1, br1, acc, 0, 0, 0);
#pragma unroll
    for (int r2 = 0; r2 < 4; ++r2) {
      const int node = nodebase + quad * 4 + r2;
      if (node < n_nodes) out[(size_t)node * FDIM + wave * 16 + m] = acc[r2];
    }
  }
}

extern "C" void kernel_launch(void* const* d_in, const int* in_sizes, int n_in,
                              void* d_out, int out_size, void* d_ws, size_t ws_size,
                              hipStream_t stream) {
  const float* x = (const float*)d_in[0];
  const int* edge_index = (const int*)d_in[1];
  const float* Wl = (const float*)d_in[2];
  const float* Wr = (const float*)d_in[3];
  float* out = (float*)d_out;

  int n_nodes = in_sizes[0] / FDIM;  // 100000
  int n_edges = in_sizes[1] / 2;     // 1200000
  const int* e_src = edge_index;
  const int* e_dst = edge_index + n_edges;

  const int NBKT = (n_nodes + NPB - 1) / NPB;  // 196

  // ws layout
  int* cursorB = (int*)d_ws;        // MAXBKT
  int* offsets = cursorB + MAXBKT;  // N+1
  int* praw = offsets + n_nodes + 2;
  int2* pairs = (int2*)(((uintptr_t)praw + 15) & ~(uintptr_t)15);  // NBKT*CAP
  int* sorted_src = (int*)(pairs + (size_t)NBKT * CAP);            // E
  ushort* xbuf = (ushort*)(((uintptr_t)(sorted_src + n_edges) + 15) &
                           ~(uintptr_t)15);   // N*64 bf16
  ushort* WlT = xbuf + (size_t)n_nodes * FDIM;  // 4096
  ushort* WrT = WlT + FDIM * FDIM;              // 4096

  // grid: full co-resident capacity (cooperative launch requires it)
  int nbpc = 0;
  hipOccupancyMaxActiveBlocksPerMultiprocessor(&nbpc, k_all, 256, 0);
  if (nbpc < 1) nbpc = 1;
  int grid = nbpc * 256;  // 256 CUs on MI355X
  const int ntiles = (n_nodes + 15) / 16;
  if (grid > ntiles) grid = ntiles;

  void* args[] = {(void*)&x,       (void*)&e_src,      (void*)&e_dst,
                  (void*)&Wl,      (void*)&Wr,         (void*)&out,
                  (void*)&xbuf,    (void*)&WlT,        (void*)&WrT,
                  (void*)&cursorB, (void*)&offsets,    (void*)&pairs,
                  (void*)&sorted_src, (void*)&n_nodes, (void*)&n_edges};
  hipLaunchCooperativeKernel((void*)k_all, dim3(grid), dim3(256), args, 0, stream);
}

// Round 10
// 183.690 us; speedup vs baseline: 2.8566x; 2.8566x over previous
//
#include <hip/hip_runtime.h>
#include <stdint.h>

// SAGEConv (mean aggr, no bias): out = segment_mean(x[src], dst) @ W_l + x @ W_r
// Pipeline (3 dispatches, no global atomics, no init pass):
//   A k_cvtpart: blocks [0,XB): x -> bf16 xb (+W transpose in block 0);
//                blocks [XB,XB+EB): partition chunk of 2048 edges into
//                bucket-grouped (dst>>9) private runs + bstart scan table.
//   B k_sub    : per bucket: gather runs -> per-node count -> LDS scan ->
//                bucket-local CSR (offsets/ends) + scatter sorted_src.
//   C k_fused  : gather-mean (wave/node-quad, 16B lanes) -> LDS bf16 tile ->
//                MFMA GEMM out = mean@Wl + x@Wr (fp32 acc).

#define FDIM 64
#define NPB 512
#define PART_T 2048
#define MAXBKT 256
#define CAP 8192

typedef __attribute__((ext_vector_type(8))) short bf16x8;
typedef __attribute__((ext_vector_type(8))) ushort ushort8v;
typedef __attribute__((ext_vector_type(4))) float f32x4;

__device__ inline ushort f2b(float v) {
  union { float f; uint32_t u; } c; c.f = v;
  return (ushort)((c.u + 0x7FFF + ((c.u >> 16) & 1)) >> 16);  // RNE
}
__device__ inline float b2f(ushort h) {
  union { uint32_t u; float f; } c; c.u = ((uint32_t)h) << 16;
  return c.f;
}

// ---- A: cvt (blocks [0,XB)) + partition (blocks [XB,XB+EB)) ----
__global__ __launch_bounds__(256) void k_cvtpart(
    const float* __restrict__ x, const int* __restrict__ esrc,
    const int* __restrict__ edst, const float* __restrict__ Wl,
    const float* __restrict__ Wr, ushort* __restrict__ xb,
    ushort* __restrict__ WlT, ushort* __restrict__ WrT,
    int2* __restrict__ pairs, int* __restrict__ bstart, int xquads, int XB,
    int E) {
  __shared__ int cnt[MAXBKT], sc[MAXBKT], excl0[MAXBKT], cursorL[MAXBKT];
  __shared__ int2 buf[PART_T];
  const int t = threadIdx.x;
  const int bid = blockIdx.x;

  if (bid < XB) {
    const int idx = bid * 256 + t;
    if (idx < xquads) {
      const float4 v = ((const float4*)x)[idx];
      ushort4 o;
      o.x = f2b(v.x); o.y = f2b(v.y); o.z = f2b(v.z); o.w = f2b(v.w);
      ((ushort4*)xb)[idx] = o;
    }
    if (bid == 0) {
      for (int i = t; i < FDIM * FDIM; i += 256) {
        const int f = i >> 6, k = i & 63;
        WlT[f * 64 + k] = f2b(Wl[k * 64 + f]);
        WrT[f * 64 + k] = f2b(Wr[k * 64 + f]);
      }
    }
    return;
  }

  const int chunk = bid - XB;
  const int base = chunk * PART_T;
  const int nvalid = min(E - base, PART_T);
  cnt[t] = 0;
  __syncthreads();

  int s[8], d[8], bk[8];
#pragma unroll
  for (int i = 0; i < 8; ++i) {
    const int e = base + i * 256 + t;
    if (e < E) {
      s[i] = esrc[e];
      d[i] = edst[e];
      bk[i] = d[i] >> 9;
      atomicAdd(&cnt[bk[i]], 1);
    } else {
      bk[i] = -1;
    }
  }
  __syncthreads();

  sc[t] = cnt[t];
  __syncthreads();
  for (int off = 1; off < MAXBKT; off <<= 1) {
    int v = (t >= off) ? sc[t - off] : 0;
    __syncthreads();
    sc[t] += v;
    __syncthreads();
  }
  excl0[t] = sc[t] - cnt[t];
  cursorL[t] = excl0[t];
  __syncthreads();

#pragma unroll
  for (int i = 0; i < 8; ++i) {
    if (bk[i] >= 0) {
      int slot = atomicAdd(&cursorL[bk[i]], 1);
      buf[slot] = make_int2(s[i], d[i]);
    }
  }
  __syncthreads();

  // private, fully coalesced run write + scan table
  for (int idx = t; idx < nvalid; idx += 256) pairs[base + idx] = buf[idx];
  bstart[chunk * 257 + t] = excl0[t];
  if (t == 0) bstart[chunk * 257 + 256] = nvalid;
}

// ---- B: per bucket: counts -> scan -> bucket-local CSR + scatter ----
__global__ __launch_bounds__(512) void k_sub(const int2* __restrict__ pairs,
                                             const int* __restrict__ bstart,
                                             int* __restrict__ offsets,
                                             int* __restrict__ ends,
                                             int* __restrict__ sorted_src,
                                             int n_nodes, int EB) {
  __shared__ int cnt[NPB];
  const int b = blockIdx.x;
  const int t = threadIdx.x;
  const int nodebase = b * NPB;
  cnt[t] = 0;
  __syncthreads();

  for (int ch = t; ch < EB; ch += 512) {
    const int* bs = bstart + ch * 257;
    const int s0 = bs[b], s1 = bs[b + 1];
    const int2* run = pairs + (size_t)ch * PART_T;
    for (int i = s0; i < s1; ++i) atomicAdd(&cnt[run[i].y - nodebase], 1);
  }
  __syncthreads();

  const int v = cnt[t];
  for (int off = 1; off < NPB; off <<= 1) {
    int add = (t >= off) ? cnt[t - off] : 0;
    __syncthreads();
    cnt[t] += add;
    __syncthreads();
  }
  const int gs = b * CAP + (cnt[t] - v);  // bucket-local CSR start
  const int node = nodebase + t;
  if (node < n_nodes) {
    offsets[node] = gs;
    ends[node] = gs + v;
  }
  __syncthreads();
  cnt[t] = gs;  // reuse as cursor
  __syncthreads();

  for (int ch = t; ch < EB; ch += 512) {
    const int* bs = bstart + ch * 257;
    const int s0 = bs[b], s1 = bs[b + 1];
    const int2* run = pairs + (size_t)ch * PART_T;
    for (int i = s0; i < s1; ++i) {
      int2 p = run[i];
      int pos = atomicAdd(&cnt[p.y - nodebase], 1);
      sorted_src[pos] = p.x;
    }
  }
}

// ---- C: fused gather-mean + MFMA GEMM (16 nodes / 256-thread block) ----
// Gather lanes: c = lane & 7 (16 B slice of 128 B row), g = lane >> 3 (8 slots)
// -> one wave load = 8 rows x 16 B = 1 KB.
__global__ __launch_bounds__(256) void k_fused(const ushort* __restrict__ xb,
                                               const int* __restrict__ offsets,
                                               const int* __restrict__ ends,
                                               const int* __restrict__ sorted_src,
                                               const ushort* __restrict__ WlT,
                                               const ushort* __restrict__ WrT,
                                               float* __restrict__ out,
                                               int n_nodes) {
  __shared__ ushort meanLds[16][88];  // stride 176 B: 16B-aligned, 2-way alias max
  const int t = threadIdx.x;
  const int wave = t >> 6;
  const int lane = t & 63;
  const int c = lane & 7;
  const int g = lane >> 3;
  const int nodebase = blockIdx.x * 16;

#pragma unroll
  for (int q = 0; q < 4; ++q) {
    const int r = wave * 4 + q;
    const int node = nodebase + r;
    if (node >= n_nodes) break;
    const int start = offsets[node];
    const int end = ends[node];
    const int degree = end - start;

    float s0 = 0.f, s1 = 0.f, s2 = 0.f, s3 = 0.f;
    float s4 = 0.f, s5 = 0.f, s6 = 0.f, s7 = 0.f;
    for (int base = start; base < end; base += 64) {
      const int e = base + lane;
      const int idx = (e < end) ? sorted_src[e] : node;  // pad = safe address
      const int nIn = min(end - base, 64);
      const int G = (nIn + 7) >> 3;
#pragma unroll 4
      for (int j = 0; j < G; ++j) {
        const int sub = 8 * j + g;
        const int se = __shfl(idx, sub, 64);
        const float wm = (sub < nIn) ? 1.0f : 0.0f;
        const ushort8v h = *(const ushort8v*)(xb + (size_t)se * FDIM + (c << 3));
        s0 = fmaf(b2f(h[0]), wm, s0);
        s1 = fmaf(b2f(h[1]), wm, s1);
        s2 = fmaf(b2f(h[2]), wm, s2);
        s3 = fmaf(b2f(h[3]), wm, s3);
        s4 = fmaf(b2f(h[4]), wm, s4);
        s5 = fmaf(b2f(h[5]), wm, s5);
        s6 = fmaf(b2f(h[6]), wm, s6);
        s7 = fmaf(b2f(h[7]), wm, s7);
      }
    }
#pragma unroll
    for (int msk = 8; msk <= 32; msk <<= 1) {
      s0 += __shfl_xor(s0, msk, 64);
      s1 += __shfl_xor(s1, msk, 64);
      s2 += __shfl_xor(s2, msk, 64);
      s3 += __shfl_xor(s3, msk, 64);
      s4 += __shfl_xor(s4, msk, 64);
      s5 += __shfl_xor(s5, msk, 64);
      s6 += __shfl_xor(s6, msk, 64);
      s7 += __shfl_xor(s7, msk, 64);
    }
    if (g == 0) {
      const float inv = 1.0f / (float)max(degree, 1);
      ushort8v mb;
      mb[0] = f2b(s0 * inv);
      mb[1] = f2b(s1 * inv);
      mb[2] = f2b(s2 * inv);
      mb[3] = f2b(s3 * inv);
      mb[4] = f2b(s4 * inv);
      mb[5] = f2b(s5 * inv);
      mb[6] = f2b(s6 * inv);
      mb[7] = f2b(s7 * inv);
      *(ushort8v*)(&meanLds[r][c << 3]) = mb;
    }
  }
  __syncthreads();

  // MFMA phase: wave w -> feature slice [w*16, w*16+16)
  const int m = lane & 15;
  const int quad = lane >> 4;
  bf16x8 am0 = *(const bf16x8*)(&meanLds[m][quad * 8]);
  bf16x8 am1 = *(const bf16x8*)(&meanLds[m][32 + quad * 8]);
  const int arow = min(nodebase + m, n_nodes - 1);
  bf16x8 ax0 = *(const bf16x8*)(xb + (size_t)arow * FDIM + quad * 8);
  bf16x8 ax1 = *(const bf16x8*)(xb + (size_t)arow * FDIM + 32 + quad * 8);
  const int f = wave * 16 + m;
  bf16x8 bl0 = *(const bf16x8*)(WlT + (size_t)f * FDIM + quad * 8);
  bf16x8 bl1 = *(const bf16x8*)(WlT + (size_t)f * FDIM + 32 + quad * 8);
  bf16x8 br0 = *(const bf16x8*)(WrT + (size_t)f * FDIM + quad * 8);
  bf16x8 br1 = *(const bf16x8*)(WrT + (size_t)f * FDIM + 32 + quad * 8);
  f32x4 acc = {0.f, 0.f, 0.f, 0.f};
  acc = __builtin_amdgcn_mfma_f32_16x16x32_bf16(am0, bl0, acc, 0, 0, 0);
  acc = __builtin_amdgcn_mfma_f32_16x16x32_bf16(am1, bl1, acc, 0, 0, 0);
  acc = __builtin_amdgcn_mfma_f32_16x16x32_bf16(ax0, br0, acc, 0, 0, 0);
  acc = __builtin_amdgcn_mfma_f32_16x16x32_bf16(ax1, br1, acc, 0, 0, 0);
#pragma unroll
  for (int r2 = 0; r2 < 4; ++r2) {
    const int node = nodebase + quad * 4 + r2;
    if (node < n_nodes) out[(size_t)node * FDIM + wave * 16 + m] = acc[r2];
  }
}

extern "C" void kernel_launch(void* const* d_in, const int* in_sizes, int n_in,
                              void* d_out, int out_size, void* d_ws, size_t ws_size,
                              hipStream_t stream) {
  const float* x = (const float*)d_in[0];
  const int* edge_index = (const int*)d_in[1];
  const float* Wl = (const float*)d_in[2];
  const float* Wr = (const float*)d_in[3];
  float* out = (float*)d_out;

  const int n_nodes = in_sizes[0] / FDIM;  // 100000
  const int n_edges = in_sizes[1] / 2;     // 1200000
  const int* e_src = edge_index;
  const int* e_dst = edge_index + n_edges;

  const int NBKT = (n_nodes + NPB - 1) / NPB;        // 196
  const int EB = (n_edges + PART_T - 1) / PART_T;    // 586
  const int xquads = n_nodes * (FDIM / 4);           // 1.6M
  const int XB = (xquads + 255) / 256;               // 6250

  // ws layout
  int* bstart = (int*)d_ws;                       // EB*257
  int* offsets = bstart + (size_t)EB * 257;       // N
  int* ends = offsets + n_nodes;                  // N
  int* praw = ends + n_nodes;
  int2* pairs = (int2*)(((uintptr_t)praw + 15) & ~(uintptr_t)15);  // EB*PART_T
  int* sorted_src = (int*)(pairs + (size_t)EB * PART_T);  // NBKT*CAP
  ushort* xbuf = (ushort*)(((uintptr_t)(sorted_src + (size_t)NBKT * CAP) + 15) &
                           ~(uintptr_t)15);       // N*64 bf16
  ushort* WlT = xbuf + (size_t)n_nodes * FDIM;    // 4096
  ushort* WrT = WlT + FDIM * FDIM;                // 4096

  k_cvtpart<<<XB + EB, 256, 0, stream>>>(x, e_src, e_dst, Wl, Wr, xbuf, WlT, WrT,
                                         pairs, bstart, xquads, XB, n_edges);
  k_sub<<<NBKT, 512, 0, stream>>>(pairs, bstart, offsets, ends, sorted_src,
                                  n_nodes, EB);
  k_fused<<<(n_nodes + 15) / 16, 256, 0, stream>>>(xbuf, offsets, ends, sorted_src,
                                                   WlT, WrT, out, n_nodes);
}